// Round 16
// baseline (341.120 us; speedup 1.0000x reference)
//
#include <hip/hip_runtime.h>
#include <hip/hip_bf16.h>
#include <stdint.h>

// MoE FFN, top-1 routing. x:[4,2048,1024] f32, 8 experts, 1024->4096->1024.
// R16: R15 + FFN2 job-table (<=256 jobs): first S=256-base tiles split-K in
//      half -> f32 partials in dead W1T region; rest full-K direct. One job
//      per CU -> makespan ~1 half/full block time. Reduce sums pairs.

#define D_MODEL 1024
#define D_FF    4096
#define NEXP    8
#define NTOK    8192
#define MAXT256 40

typedef __attribute__((ext_vector_type(8))) short bf16x8;
typedef __attribute__((ext_vector_type(8))) unsigned short u16x8;
typedef __attribute__((ext_vector_type(4))) unsigned short u16x4;
typedef __attribute__((ext_vector_type(4))) float f32x4;

// ---- workspace layout (bytes) ----
#define OFF_META 0u
#define OFF_TOPI 4096u
#define OFF_PERM 36864u
#define OFF_POS  69632u
#define OFF_XG   131072u                     // 8448*1024*2
#define OFF_H    17432576u                   // 8448*4096*2
#define OFF_W1T  86638592u                   // 8*4096*1024*2 (FFN2 partials after FFN1)
#define OFF_W2T  153747456u                  // 8*1024*4096*2

__device__ __forceinline__ unsigned short f2bf(float f) {
  unsigned int u = __builtin_bit_cast(unsigned int, f);
  unsigned int r = (u + 0x7FFFu + ((u >> 16) & 1u)) >> 16;
  return (unsigned short)r;
}

typedef const __attribute__((address_space(1))) unsigned int* gas_u32;
typedef __attribute__((address_space(3))) unsigned int* las_u32;

__device__ __forceinline__ void gload16(const void* g, void* l) {
  __builtin_amdgcn_global_load_lds((gas_u32)g, (las_u32)l, 16, 0, 0);
}

__device__ __forceinline__ int xcd_swz(int orig, int nwg) {
  int q = nwg >> 3, r = nwg & 7;
  int xcd = orig & 7, lid = orig >> 3;
  return (xcd < r ? xcd * (q + 1) : r * (q + 1) + (xcd - r) * q) + lid;
}

// ---- het kernel 1: gate (blocks 0..2047) ∥ w1 transconv (blocks 2048..10239)
__global__ __launch_bounds__(256) void het_gate_w1t(const float* __restrict__ x,
    const float* __restrict__ gw, const float* __restrict__ gb,
    const float* __restrict__ eb, int* __restrict__ topi,
    const float* __restrict__ w1, unsigned short* __restrict__ w1t) {
  __shared__ float tile[64][65];
  int bid = blockIdx.x;
  int tid = threadIdx.x;
  if (bid < 2048) {
    int wid = tid >> 6, lane = tid & 63;
    int t = bid * 4 + wid;
    const float* xr = x + (size_t)t * D_MODEL;
    double p[NEXP];
#pragma unroll
    for (int e = 0; e < NEXP; ++e) p[e] = 0.0;
#pragma unroll
    for (int j = 0; j < 4; ++j) {
      int c = (lane + j * 64) * 4;
      f32x4 xv = *(const f32x4*)(xr + c);
#pragma unroll
      for (int e = 0; e < NEXP; ++e) {
        f32x4 gv = *(const f32x4*)(gw + e * D_MODEL + c);
#pragma unroll
        for (int q = 0; q < 4; ++q) p[e] += (double)xv[q] * (double)gv[q];
      }
    }
#pragma unroll
    for (int e = 0; e < NEXP; ++e) {
      for (int off = 32; off; off >>= 1) p[e] += __shfl_xor(p[e], off, 64);
    }
    if (lane == 0) {
      double best = -1e300; int bi = 0;
#pragma unroll
      for (int e = 0; e < NEXP; ++e) {
        double v = p[e] + (double)gb[e] + (double)eb[e];
        if (v > best) { best = v; bi = e; }
      }
      topi[t] = bi;
    }
  } else {
    int id = bid - 2048;
    int e = id >> 10, rem = id & 1023;
    const int R = 1024, C = 4096;
    int c0 = (rem & 63) * 64, r0 = (rem >> 6) * 64;
    const float* src = w1 + (size_t)e * R * C;
    unsigned short* dst = w1t + (size_t)e * R * C;
    int rr = tid >> 4, cc4 = (tid & 15) * 4;
#pragma unroll
    for (int i = 0; i < 4; ++i) {
      f32x4 v = *(const f32x4*)(src + (size_t)(r0 + rr + i * 16) * C + c0 + cc4);
#pragma unroll
      for (int j = 0; j < 4; ++j) tile[rr + i * 16][cc4 + j] = v[j];
    }
    __syncthreads();
    int cc = tid >> 3, rr8 = (tid & 7) * 8;
#pragma unroll
    for (int i = 0; i < 2; ++i) {
      int c = cc + i * 32;
      u16x8 u;
#pragma unroll
      for (int j = 0; j < 8; ++j) u[j] = f2bf(tile[rr8 + j][c]);
      *(u16x8*)(dst + (size_t)(c0 + c) * R + r0 + rr8) = u;
    }
  }
}

// ---- rank kernel: counts/offsets/tilemap/pos/perm + FFN2 job table ----
__global__ __launch_bounds__(1024) void rank_kernel(const int* __restrict__ topi,
    int* __restrict__ meta, int* __restrict__ pos, int* __restrict__ perm) {
  __shared__ int hist[NEXP][1024];
  __shared__ int offs_s[NEXP + 1];
  int tid = threadIdx.x;
  int te[8], loc[NEXP], run[NEXP];
#pragma unroll
  for (int e = 0; e < NEXP; ++e) loc[e] = 0;
#pragma unroll
  for (int j = 0; j < 8; ++j) {
    te[j] = topi[tid * 8 + j];
#pragma unroll
    for (int e = 0; e < NEXP; ++e) loc[e] += (te[j] == e) ? 1 : 0;
  }
#pragma unroll
  for (int e = 0; e < NEXP; ++e) { run[e] = loc[e]; hist[e][tid] = run[e]; }
  __syncthreads();
  for (int s = 1; s < 1024; s <<= 1) {
    int v[NEXP];
#pragma unroll
    for (int e = 0; e < NEXP; ++e) v[e] = (tid >= s) ? hist[e][tid - s] : 0;
    __syncthreads();
#pragma unroll
    for (int e = 0; e < NEXP; ++e) { run[e] += v[e]; hist[e][tid] = run[e]; }
    __syncthreads();
  }
  if (tid == 1023) {
    int o = 0, nt = 0;
    for (int e = 0; e < NEXP; ++e) {
      offs_s[e] = o;
      meta[e] = run[e];
      meta[8 + e] = o;
      o += run[e];
    }
    offs_s[NEXP] = o; meta[16] = o;
    for (int e = 0; e < NEXP; ++e) {
      int ntile = (run[e] + 255) >> 8;
      for (int j = 0; j < ntile; ++j) { meta[32 + nt] = e; meta[112 + nt] = j; ++nt; }
    }
    meta[25] = nt;
    // FFN2 job table: base jobs nb-outer/t-inner; first S split K in half.
    int base = nt * 4;
    int S = 256 - base;
    if (S > base) S = base;
    if (S < 0) S = 0;
    int nj = 0, pair = 0;
    for (int i = 0; i < base; ++i) {
      int nb = i / nt, t = i % nt;
      if (i < S) {
        meta[512 + nj] = t | (nb << 8) | (1 << 16) | (pair << 20); ++nj;
        meta[512 + nj] = t | (nb << 8) | (2 << 16) | (pair << 20); ++nj;
        meta[192 + pair] = t | (nb << 8);
        ++pair;
      } else {
        meta[512 + nj] = t | (nb << 8); ++nj;
      }
    }
    meta[27] = nj;
    meta[28] = pair;
  }
  __syncthreads();
  int base[NEXP];
#pragma unroll
  for (int e = 0; e < NEXP; ++e) base[e] = offs_s[e] + run[e] - loc[e];
#pragma unroll
  for (int j = 0; j < 8; ++j) {
    int tok = tid * 8 + j, pj = 0;
#pragma unroll
    for (int e = 0; e < NEXP; ++e) {
      if (te[j] == e) pj = base[e];
      base[e] += (te[j] == e) ? 1 : 0;
    }
    pos[tok] = pj;
    perm[pj] = tok;
  }
}

// -------- scatter tokens into per-expert contiguous rows, f32 -> bf16 --------
__global__ __launch_bounds__(256) void scatter_kernel(const float* __restrict__ x,
    const int* __restrict__ pos, unsigned short* __restrict__ xg) {
  int t = blockIdx.x;
  int p = pos[t];
  const float* xr = x + (size_t)t * D_MODEL;
  unsigned short* orow = xg + (size_t)p * D_MODEL;
  int c = threadIdx.x * 4;
  f32x4 v = *(const f32x4*)(xr + c);
  u16x4 u;
#pragma unroll
  for (int j = 0; j < 4; ++j) u[j] = f2bf(v[j]);
  *(u16x4*)(orow + c) = u;
}

// ---------------- shared GEMM schedule macros (R9, proven) ------------------
#define SBAR() { __builtin_amdgcn_sched_barrier(0); __builtin_amdgcn_s_barrier(); __builtin_amdgcn_sched_barrier(0); }
#define WAIT_VM(N) { asm volatile("s_waitcnt vmcnt(" #N ")" ::: "memory"); __builtin_amdgcn_sched_barrier(0); }

// ---- het kernel 2: FFN1 GEMM (blocks 0..639) + w2 transconv (640..4735) ----
__global__ __launch_bounds__(512, 1) void ffn1_het(
    const unsigned short* __restrict__ A, const unsigned short* __restrict__ Bt,
    const float* __restrict__ bias, const int* __restrict__ meta,
    unsigned short* __restrict__ H,
    const float* __restrict__ w2, unsigned short* __restrict__ w2t) {
  __shared__ char lds[131072];
  int bid = blockIdx.x;
  int tid = threadIdx.x;

  if (bid >= MAXT256 * 16) {
    int tsel = tid >> 8, tid2 = tid & 255;
    int tid8 = (bid - MAXT256 * 16) * 2 + tsel;
    int e = tid8 >> 10, rem = tid8 & 1023;
    const int R = 4096, C = 1024;
    int c0 = (rem & 15) * 64, r0 = (rem >> 4) * 64;
    const float* src = w2 + (size_t)e * R * C;
    unsigned short* dst = w2t + (size_t)e * R * C;
    float (*tile)[65] = (float(*)[65])(lds + tsel * 20480);
    int rr = tid2 >> 4, cc4 = (tid2 & 15) * 4;
#pragma unroll
    for (int i = 0; i < 4; ++i) {
      f32x4 v = *(const f32x4*)(src + (size_t)(r0 + rr + i * 16) * C + c0 + cc4);
#pragma unroll
      for (int j = 0; j < 4; ++j) tile[rr + i * 16][cc4 + j] = v[j];
    }
    __syncthreads();
    int cc = tid2 >> 3, rr8 = (tid2 & 7) * 8;
#pragma unroll
    for (int i = 0; i < 2; ++i) {
      int c = cc + i * 32;
      u16x8 u;
#pragma unroll
      for (int j = 0; j < 8; ++j) u[j] = f2bf(tile[rr8 + j][c]);
      *(u16x8*)(dst + (size_t)(c0 + c) * R + r0 + rr8) = u;
    }
    return;
  }

  // ------------------------- FFN1 GEMM (R9 body) -------------------------
  constexpr int KDIM = D_MODEL, NDIM = D_FF;
  constexpr int NT = KDIM / 64;
  constexpr int SK = KDIM * 2;
  const int NP = NDIM / 256;
  int ntiles = meta[25];
  int nwg = ntiles * NP;
  int orig = bid;
  if (orig >= nwg) return;
  int wid = xcd_swz(orig, nwg);
  int t = wid % ntiles, nb = wid / ntiles;

  int e = meta[32 + t];
  int lm = meta[112 + t];
  int off = meta[8 + e];
  int rowsValid = meta[9 + e] - off - lm * 256;
  int m0 = off + lm * 256;

  int lane = tid & 63, wv = tid >> 6;
  int waveM = wv >> 2, waveN = wv & 3;
  int lr = lane & 15, lg = lane >> 4;

  const char* aBase = (const char*)(A + (size_t)m0 * KDIM);
  const char* bBase = (const char*)(Bt + ((size_t)e * NDIM + nb * 256) * KDIM);

  const int o0 = tid * 16, o1 = o0 + 8192;
  const int lw0 = o0 >> 7, lw1 = o1 >> 7;
  const int co0 = (o0 & 127) ^ ((lw0 & 7) << 4);
  const int co1 = (o1 & 127) ^ ((lw1 & 7) << 4);
  const int mA0 = (lw0 >> 6) * 128 + (lw0 & 63), mA1 = (lw1 >> 6) * 128 + (lw1 & 63);
  const int nB0 = (lw0 >> 5) * 64 + (lw0 & 31), nB1 = (lw1 >> 5) * 64 + (lw1 & 31);

#define ST_A(D, R, KT) { \
    char* _d = lds + (D) * 65536 + (R) * 16384; \
    gload16(aBase + (size_t)(mA0 + (R) * 64) * SK + (KT) * 128 + co0, _d + o0); \
    gload16(aBase + (size_t)(mA1 + (R) * 64) * SK + (KT) * 128 + co1, _d + o1); }
#define ST_B(D, R, KT) { \
    char* _d = lds + (D) * 65536 + 32768 + (R) * 16384; \
    gload16(bBase + (size_t)(nB0 + (R) * 32) * SK + (KT) * 128 + co0, _d + o0); \
    gload16(bBase + (size_t)(nB1 + (R) * 32) * SK + (KT) * 128 + co1, _d + o1); }

  bf16x8 a[4][2], b0[2][2], b1[2][2];
#define LD_A(D, MH) { \
    const char* _b = lds + (D) * 65536 + (MH) * 16384; \
    _Pragma("unroll") for (int mfi = 0; mfi < 4; ++mfi) \
    _Pragma("unroll") for (int kq = 0; kq < 2; ++kq) { \
      int _o = (waveM * 64 + mfi * 16 + lr) * 128 + kq * 64 + lg * 16; \
      _o ^= ((_o >> 7) & 7) << 4; \
      a[mfi][kq] = *(const bf16x8*)(_b + _o); } }
#define LD_B(D, NH, BV) { \
    const char* _b = lds + (D) * 65536 + 32768 + (NH) * 16384; \
    _Pragma("unroll") for (int nfi = 0; nfi < 2; ++nfi) \
    _Pragma("unroll") for (int kq = 0; kq < 2; ++kq) { \
      int _o = (waveN * 32 + nfi * 16 + lr) * 128 + kq * 64 + lg * 16; \
      _o ^= ((_o >> 7) & 7) << 4; \
      BV[nfi][kq] = *(const bf16x8*)(_b + _o); } }

  f32x4 acc[8][4];
#pragma unroll
  for (int i = 0; i < 8; ++i)
#pragma unroll
    for (int j = 0; j < 4; ++j) acc[i][j] = (f32x4){0.f, 0.f, 0.f, 0.f};

#define MM(MH, NH, BV) { \
    __builtin_amdgcn_s_setprio(1); \
    _Pragma("unroll") for (int mfi = 0; mfi < 4; ++mfi) \
    _Pragma("unroll") for (int nfi = 0; nfi < 2; ++nfi) \
    _Pragma("unroll") for (int kq = 0; kq < 2; ++kq) \
      acc[(MH) * 4 + mfi][(NH) * 2 + nfi] = __builtin_amdgcn_mfma_f32_16x16x32_bf16( \
          a[mfi][kq], BV[nfi][kq], acc[(MH) * 4 + mfi][(NH) * 2 + nfi], 0, 0, 0); \
    __builtin_amdgcn_s_setprio(0); }

  {
    int k1 = NT > 1 ? 1 : 0;
    ST_A(0, 0, 0); ST_B(0, 1, 0); ST_A(0, 1, 0); ST_B(0, 0, 0);
    ST_A(1, 0, k1); ST_B(1, 1, k1); ST_A(1, 1, k1);
  }
  WAIT_VM(6); SBAR();

  for (int T = 0; T < NT; ++T) {
    int d = T & 1, dn = d ^ 1;
    int tp1 = T + 1 < NT ? T + 1 : T;
    int tp2 = T + 2 < NT ? T + 2 : T;
    LD_A(d, 0); LD_B(d, 0, b0);
    ST_B(dn, 0, tp1);
    SBAR();
    MM(0, 0, b0);
    SBAR();
    LD_B(d, 1, b1);
    ST_A(d, 0, tp2);
    SBAR();
    MM(0, 1, b1);
    SBAR();
    LD_A(d, 1);
    ST_B(d, 1, tp2);
    SBAR();
    MM(1, 1, b1);
    SBAR();
    ST_A(d, 1, tp2);
    SBAR();
    MM(1, 0, b0);
    WAIT_VM(6);
    SBAR();
  }
  asm volatile("s_waitcnt vmcnt(0)" ::: "memory");

  int cb = nb * 256 + waveN * 64;
#pragma unroll
  for (int mf = 0; mf < 8; ++mf) {
#pragma unroll
    for (int rg = 0; rg < 4; ++rg) {
      int rowt = waveM * 128 + mf * 16 + lg * 4 + rg;
      if (rowt >= rowsValid) continue;
      size_t ro = (size_t)(m0 + rowt) * NDIM;
#pragma unroll
      for (int nf = 0; nf < 4; ++nf) {
        int col = cb + nf * 16 + lr;
        float v = acc[mf][nf][rg] + bias[e * NDIM + col];
        H[ro + col] = f2bf(fmaxf(v, 0.f));
      }
    }
  }
#undef ST_A
#undef ST_B
#undef LD_A
#undef LD_B
#undef MM
}

// ---- FFN2: job-table GEMM. Full jobs -> Out (+bias, perm). Split jobs ->
// f32 partial tiles in Part (pair*2+half). K range from job record. ----
__global__ __launch_bounds__(512, 1) void gemm8_ffn2(
    const unsigned short* __restrict__ A, const unsigned short* __restrict__ Bt,
    const float* __restrict__ bias, const int* __restrict__ meta,
    const int* __restrict__ perm, float* __restrict__ Out,
    float* __restrict__ Part) {
  constexpr int KDIM = D_FF, NDIM = D_MODEL;
  constexpr int SK = KDIM * 2;
  int njobs = meta[27];
  int orig = blockIdx.x;
  if (orig >= njobs) return;
  int wid = xcd_swz(orig, njobs);
  int rec = meta[512 + wid];
  int t = rec & 255, nb = (rec >> 8) & 255;
  int ks = (rec >> 16) & 15, pair = rec >> 20;
  int NTloc = ks ? 32 : 64;
  int k0 = (ks == 2) ? 32 : 0;               // K-tile offset

  int e = meta[32 + t];
  int lm = meta[112 + t];
  int off = meta[8 + e];
  int rowsValid = meta[9 + e] - off - lm * 256;
  int m0 = off + lm * 256;

  __shared__ char lds[131072];

  int tid = threadIdx.x;
  int lane = tid & 63, wv = tid >> 6;
  int waveM = wv >> 2, waveN = wv & 3;
  int lr = lane & 15, lg = lane >> 4;

  const char* aBase = (const char*)(A + (size_t)m0 * KDIM) + (size_t)k0 * 128;
  const char* bBase = (const char*)(Bt + ((size_t)e * NDIM + nb * 256) * KDIM) + (size_t)k0 * 128;

  const int o0 = tid * 16, o1 = o0 + 8192;
  const int lw0 = o0 >> 7, lw1 = o1 >> 7;
  const int co0 = (o0 & 127) ^ ((lw0 & 7) << 4);
  const int co1 = (o1 & 127) ^ ((lw1 & 7) << 4);
  const int mA0 = (lw0 >> 6) * 128 + (lw0 & 63), mA1 = (lw1 >> 6) * 128 + (lw1 & 63);
  const int nB0 = (lw0 >> 5) * 64 + (lw0 & 31), nB1 = (lw1 >> 5) * 64 + (lw1 & 31);

#define ST_A(D, R, KT) { \
    char* _d = lds + (D) * 65536 + (R) * 16384; \
    gload16(aBase + (size_t)(mA0 + (R) * 64) * SK + (KT) * 128 + co0, _d + o0); \
    gload16(aBase + (size_t)(mA1 + (R) * 64) * SK + (KT) * 128 + co1, _d + o1); }
#define ST_B(D, R, KT) { \
    char* _d = lds + (D) * 65536 + 32768 + (R) * 16384; \
    gload16(bBase + (size_t)(nB0 + (R) * 32) * SK + (KT) * 128 + co0, _d + o0); \
    gload16(bBase + (size_t)(nB1 + (R) * 32) * SK + (KT) * 128 + co1, _d + o1); }

  bf16x8 a[4][2], b0[2][2], b1[2][2];
#define LD_A(D, MH) { \
    const char* _b = lds + (D) * 65536 + (MH) * 16384; \
    _Pragma("unroll") for (int mfi = 0; mfi < 4; ++mfi) \
    _Pragma("unroll") for (int kq = 0; kq < 2; ++kq) { \
      int _o = (waveM * 64 + mfi * 16 + lr) * 128 + kq * 64 + lg * 16; \
      _o ^= ((_o >> 7) & 7) << 4; \
      a[mfi][kq] = *(const bf16x8*)(_b + _o); } }
#define LD_B(D, NH, BV) { \
    const char* _b = lds + (D) * 65536 + 32768 + (NH) * 16384; \
    _Pragma("unroll") for (int nfi = 0; nfi < 2; ++nfi) \
    _Pragma("unroll") for (int kq = 0; kq < 2; ++kq) { \
      int _o = (waveN * 32 + nfi * 16 + lr) * 128 + kq * 64 + lg * 16; \
      _o ^= ((_o >> 7) & 7) << 4; \
      BV[nfi][kq] = *(const bf16x8*)(_b + _o); } }

  f32x4 acc[8][4];
#pragma unroll
  for (int i = 0; i < 8; ++i)
#pragma unroll
    for (int j = 0; j < 4; ++j) acc[i][j] = (f32x4){0.f, 0.f, 0.f, 0.f};

#define MM(MH, NH, BV) { \
    __builtin_amdgcn_s_setprio(1); \
    _Pragma("unroll") for (int mfi = 0; mfi < 4; ++mfi) \
    _Pragma("unroll") for (int nfi = 0; nfi < 2; ++nfi) \
    _Pragma("unroll") for (int kq = 0; kq < 2; ++kq) \
      acc[(MH) * 4 + mfi][(NH) * 2 + nfi] = __builtin_amdgcn_mfma_f32_16x16x32_bf16( \
          a[mfi][kq], BV[nfi][kq], acc[(MH) * 4 + mfi][(NH) * 2 + nfi], 0, 0, 0); \
    __builtin_amdgcn_s_setprio(0); }

  {
    ST_A(0, 0, 0); ST_B(0, 1, 0); ST_A(0, 1, 0); ST_B(0, 0, 0);
    ST_A(1, 0, 1); ST_B(1, 1, 1); ST_A(1, 1, 1);
  }
  WAIT_VM(6); SBAR();

  for (int T = 0; T < NTloc; ++T) {
    int d = T & 1, dn = d ^ 1;
    int tp1 = T + 1 < NTloc ? T + 1 : T;
    int tp2 = T + 2 < NTloc ? T + 2 : T;
    LD_A(d, 0); LD_B(d, 0, b0);
    ST_B(dn, 0, tp1);
    SBAR();
    MM(0, 0, b0);
    SBAR();
    LD_B(d, 1, b1);
    ST_A(d, 0, tp2);
    SBAR();
    MM(0, 1, b1);
    SBAR();
    LD_A(d, 1);
    ST_B(d, 1, tp2);
    SBAR();
    MM(1, 1, b1);
    SBAR();
    ST_A(d, 1, tp2);
    SBAR();
    MM(1, 0, b0);
    WAIT_VM(6);
    SBAR();
  }
  asm volatile("s_waitcnt vmcnt(0)" ::: "memory");

  int cbl = waveN * 64;                       // col within 256-tile
#pragma unroll
  for (int mf = 0; mf < 8; ++mf) {
#pragma unroll
    for (int rg = 0; rg < 4; ++rg) {
      int rowt = waveM * 128 + mf * 16 + lg * 4 + rg;
      if (rowt >= rowsValid) continue;
      if (ks == 0) {
        int tok = perm[m0 + rowt];
        size_t ro = (size_t)tok * NDIM;
#pragma unroll
        for (int nf = 0; nf < 4; ++nf) {
          int col = nb * 256 + cbl + nf * 16 + lr;
          Out[ro + col] = acc[mf][nf][rg] + bias[e * NDIM + col];
        }
      } else {
        float* pb = Part + (((size_t)(pair * 2 + (ks - 1))) << 16);
#pragma unroll
        for (int nf = 0; nf < 4; ++nf) {
          int col = cbl + nf * 16 + lr;
          pb[rowt * 256 + col] = acc[mf][nf][rg];
        }
      }
    }
  }
#undef ST_A
#undef ST_B
#undef LD_A
#undef LD_B
#undef MM
}

// ---- reduce: Out[perm[m0+row]][nb*256+col] = part0 + part1 + bias ----
__global__ __launch_bounds__(256) void reduce_kernel(
    const float* __restrict__ part, const int* __restrict__ meta,
    const int* __restrict__ perm, const float* __restrict__ b2,
    float* __restrict__ out) {
  int pair = blockIdx.x >> 6, c = blockIdx.x & 63;
  if (pair >= meta[28]) return;
  int rec = meta[192 + pair];
  int t = rec & 255, nb = rec >> 8;
  int e = meta[32 + t];
  int lm = meta[112 + t];
  int off = meta[8 + e];
  int rowsValid = meta[9 + e] - off - lm * 256;
  int m0 = off + lm * 256;
  int idx = c * 1024 + threadIdx.x * 4;
  int row = idx >> 8, col = idx & 255;
  if (row >= rowsValid) return;
  f32x4 a0 = *(const f32x4*)(part + (((size_t)pair * 2) << 16) + idx);
  f32x4 a1 = *(const f32x4*)(part + (((size_t)pair * 2 + 1) << 16) + idx);
  f32x4 bb = *(const f32x4*)(b2 + e * D_MODEL + nb * 256 + col);
  int tok = perm[m0 + row];
  f32x4 r;
#pragma unroll
  for (int j = 0; j < 4; ++j) r[j] = a0[j] + a1[j] + bb[j];
  *(f32x4*)(out + (size_t)tok * D_MODEL + nb * 256 + col) = r;
}

extern "C" void kernel_launch(void* const* d_in, const int* in_sizes, int n_in,
                              void* d_out, int out_size, void* d_ws, size_t ws_size,
                              hipStream_t stream) {
  const float* x  = (const float*)d_in[0];
  const float* gw = (const float*)d_in[1];
  const float* gb = (const float*)d_in[2];
  const float* eb = (const float*)d_in[3];
  const float* w1 = (const float*)d_in[4];
  const float* b1 = (const float*)d_in[5];
  const float* w2 = (const float*)d_in[6];
  const float* b2 = (const float*)d_in[7];
  float* out = (float*)d_out;

  char* ws = (char*)d_ws;
  int* meta = (int*)(ws + OFF_META);
  int* topi = (int*)(ws + OFF_TOPI);
  int* perm = (int*)(ws + OFF_PERM);
  int* pos  = (int*)(ws + OFF_POS);
  unsigned short* xg  = (unsigned short*)(ws + OFF_XG);
  unsigned short* h   = (unsigned short*)(ws + OFF_H);
  unsigned short* w1t = (unsigned short*)(ws + OFF_W1T);
  float*          part = (float*)(ws + OFF_W1T);   // dead after FFN1
  unsigned short* w2t = (unsigned short*)(ws + OFF_W2T);

  hipLaunchKernelGGL(het_gate_w1t, dim3(2048 + 8192), dim3(256), 0, stream,
                     x, gw, gb, eb, topi, w1, w1t);
  hipLaunchKernelGGL(rank_kernel, dim3(1), dim3(1024), 0, stream, topi, meta, pos, perm);
  hipLaunchKernelGGL(scatter_kernel, dim3(NTOK), dim3(256), 0, stream, x, pos, xg);
  hipLaunchKernelGGL(ffn1_het, dim3(MAXT256 * 16 + 4096), dim3(512), 0, stream,
                     xg, w1t, b1, meta, h, w2, w2t);
  hipLaunchKernelGGL(gemm8_ffn2, dim3(256), dim3(512), 0, stream,
                     h, w2t, b2, meta, perm, out, part);
  hipLaunchKernelGGL(reduce_kernel, dim3(128 * 64), dim3(256), 0, stream,
                     part, meta, perm, b2, out);
}

// Round 17
// 295.711 us; speedup vs baseline: 1.1536x; 1.1536x over previous
//
#include <hip/hip_runtime.h>
#include <hip/hip_bf16.h>
#include <stdint.h>

// MoE FFN, top-1 routing. x:[4,2048,1024] f32, 8 experts, 1024->4096->1024.
// R17: R15 + t-outer/nb-inner job decode in both GEMMs (concurrent blocks on
//      an XCD share A-slabs in lockstep via L2; cuts per-XCD L3 flow ~2.5x).

#define D_MODEL 1024
#define D_FF    4096
#define NEXP    8
#define NTOK    8192
#define MAXT256 40

typedef __attribute__((ext_vector_type(8))) short bf16x8;
typedef __attribute__((ext_vector_type(8))) unsigned short u16x8;
typedef __attribute__((ext_vector_type(4))) unsigned short u16x4;
typedef __attribute__((ext_vector_type(4))) float f32x4;

// ---- workspace layout (bytes) ----
#define OFF_META 0u
#define OFF_TOPI 4096u
#define OFF_PERM 36864u
#define OFF_POS  69632u
#define OFF_XG   131072u                     // 8448*1024*2
#define OFF_H    17432576u                   // 8448*4096*2
#define OFF_W1T  86638592u                   // 8*4096*1024*2
#define OFF_W2T  153747456u                  // 8*1024*4096*2

__device__ __forceinline__ unsigned short f2bf(float f) {
  unsigned int u = __builtin_bit_cast(unsigned int, f);
  unsigned int r = (u + 0x7FFFu + ((u >> 16) & 1u)) >> 16;
  return (unsigned short)r;
}

typedef const __attribute__((address_space(1))) unsigned int* gas_u32;
typedef __attribute__((address_space(3))) unsigned int* las_u32;

__device__ __forceinline__ void gload16(const void* g, void* l) {
  __builtin_amdgcn_global_load_lds((gas_u32)g, (las_u32)l, 16, 0, 0);
}

__device__ __forceinline__ int xcd_swz(int orig, int nwg) {
  int q = nwg >> 3, r = nwg & 7;
  int xcd = orig & 7, lid = orig >> 3;
  return (xcd < r ? xcd * (q + 1) : r * (q + 1) + (xcd - r) * q) + lid;
}

// ---- het kernel 1: gate (blocks 0..2047) ∥ w1 transconv (blocks 2048..10239)
__global__ __launch_bounds__(256) void het_gate_w1t(const float* __restrict__ x,
    const float* __restrict__ gw, const float* __restrict__ gb,
    const float* __restrict__ eb, int* __restrict__ topi,
    const float* __restrict__ w1, unsigned short* __restrict__ w1t) {
  __shared__ float tile[64][65];
  int bid = blockIdx.x;
  int tid = threadIdx.x;
  if (bid < 2048) {
    int wid = tid >> 6, lane = tid & 63;
    int t = bid * 4 + wid;
    const float* xr = x + (size_t)t * D_MODEL;
    double p[NEXP];
#pragma unroll
    for (int e = 0; e < NEXP; ++e) p[e] = 0.0;
#pragma unroll
    for (int j = 0; j < 4; ++j) {
      int c = (lane + j * 64) * 4;
      f32x4 xv = *(const f32x4*)(xr + c);
#pragma unroll
      for (int e = 0; e < NEXP; ++e) {
        f32x4 gv = *(const f32x4*)(gw + e * D_MODEL + c);
#pragma unroll
        for (int q = 0; q < 4; ++q) p[e] += (double)xv[q] * (double)gv[q];
      }
    }
#pragma unroll
    for (int e = 0; e < NEXP; ++e) {
      for (int off = 32; off; off >>= 1) p[e] += __shfl_xor(p[e], off, 64);
    }
    if (lane == 0) {
      double best = -1e300; int bi = 0;
#pragma unroll
      for (int e = 0; e < NEXP; ++e) {
        double v = p[e] + (double)gb[e] + (double)eb[e];
        if (v > best) { best = v; bi = e; }
      }
      topi[t] = bi;
    }
  } else {
    int id = bid - 2048;
    int e = id >> 10, rem = id & 1023;
    const int R = 1024, C = 4096;
    int c0 = (rem & 63) * 64, r0 = (rem >> 6) * 64;
    const float* src = w1 + (size_t)e * R * C;
    unsigned short* dst = w1t + (size_t)e * R * C;
    int rr = tid >> 4, cc4 = (tid & 15) * 4;
#pragma unroll
    for (int i = 0; i < 4; ++i) {
      f32x4 v = *(const f32x4*)(src + (size_t)(r0 + rr + i * 16) * C + c0 + cc4);
#pragma unroll
      for (int j = 0; j < 4; ++j) tile[rr + i * 16][cc4 + j] = v[j];
    }
    __syncthreads();
    int cc = tid >> 3, rr8 = (tid & 7) * 8;
#pragma unroll
    for (int i = 0; i < 2; ++i) {
      int c = cc + i * 32;
      u16x8 u;
#pragma unroll
      for (int j = 0; j < 8; ++j) u[j] = f2bf(tile[rr8 + j][c]);
      *(u16x8*)(dst + (size_t)(c0 + c) * R + r0 + rr8) = u;
    }
  }
}

// ---- rank kernel: 1 block, 1024 threads. counts/offsets/tilemap/pos/perm ----
__global__ __launch_bounds__(1024) void rank_kernel(const int* __restrict__ topi,
    int* __restrict__ meta, int* __restrict__ pos, int* __restrict__ perm) {
  __shared__ int hist[NEXP][1024];
  __shared__ int offs_s[NEXP + 1];
  int tid = threadIdx.x;
  int te[8], loc[NEXP], run[NEXP];
#pragma unroll
  for (int e = 0; e < NEXP; ++e) loc[e] = 0;
#pragma unroll
  for (int j = 0; j < 8; ++j) {
    te[j] = topi[tid * 8 + j];
#pragma unroll
    for (int e = 0; e < NEXP; ++e) loc[e] += (te[j] == e) ? 1 : 0;
  }
#pragma unroll
  for (int e = 0; e < NEXP; ++e) { run[e] = loc[e]; hist[e][tid] = run[e]; }
  __syncthreads();
  for (int s = 1; s < 1024; s <<= 1) {
    int v[NEXP];
#pragma unroll
    for (int e = 0; e < NEXP; ++e) v[e] = (tid >= s) ? hist[e][tid - s] : 0;
    __syncthreads();
#pragma unroll
    for (int e = 0; e < NEXP; ++e) { run[e] += v[e]; hist[e][tid] = run[e]; }
    __syncthreads();
  }
  if (tid == 1023) {
    int o = 0, nt = 0;
    for (int e = 0; e < NEXP; ++e) {
      offs_s[e] = o;
      meta[e] = run[e];
      meta[8 + e] = o;
      o += run[e];
    }
    offs_s[NEXP] = o; meta[16] = o;
    for (int e = 0; e < NEXP; ++e) {
      int ntile = (run[e] + 255) >> 8;        // 256-row m-tiles
      for (int j = 0; j < ntile; ++j) { meta[32 + nt] = e; meta[112 + nt] = j; ++nt; }
    }
    meta[25] = nt;
  }
  __syncthreads();
  int base[NEXP];
#pragma unroll
  for (int e = 0; e < NEXP; ++e) base[e] = offs_s[e] + run[e] - loc[e];
#pragma unroll
  for (int j = 0; j < 8; ++j) {
    int tok = tid * 8 + j, pj = 0;
#pragma unroll
    for (int e = 0; e < NEXP; ++e) {
      if (te[j] == e) pj = base[e];
      base[e] += (te[j] == e) ? 1 : 0;
    }
    pos[tok] = pj;
    perm[pj] = tok;
  }
}

// -------- scatter tokens into per-expert contiguous rows, f32 -> bf16 --------
__global__ __launch_bounds__(256) void scatter_kernel(const float* __restrict__ x,
    const int* __restrict__ pos, unsigned short* __restrict__ xg) {
  int t = blockIdx.x;
  int p = pos[t];
  const float* xr = x + (size_t)t * D_MODEL;
  unsigned short* orow = xg + (size_t)p * D_MODEL;
  int c = threadIdx.x * 4;
  f32x4 v = *(const f32x4*)(xr + c);
  u16x4 u;
#pragma unroll
  for (int j = 0; j < 4; ++j) u[j] = f2bf(v[j]);
  *(u16x4*)(orow + c) = u;
}

// ---------------- shared GEMM schedule macros (R9, proven) ------------------
#define SBAR() { __builtin_amdgcn_sched_barrier(0); __builtin_amdgcn_s_barrier(); __builtin_amdgcn_sched_barrier(0); }
#define WAIT_VM(N) { asm volatile("s_waitcnt vmcnt(" #N ")" ::: "memory"); __builtin_amdgcn_sched_barrier(0); }

// ---- het kernel 2: FFN1 GEMM (blocks 0..639) + w2 transconv (640..4735) ----
__global__ __launch_bounds__(512, 1) void ffn1_het(
    const unsigned short* __restrict__ A, const unsigned short* __restrict__ Bt,
    const float* __restrict__ bias, const int* __restrict__ meta,
    unsigned short* __restrict__ H,
    const float* __restrict__ w2, unsigned short* __restrict__ w2t) {
  __shared__ char lds[131072];
  int bid = blockIdx.x;
  int tid = threadIdx.x;

  if (bid >= MAXT256 * 16) {
    int tsel = tid >> 8, tid2 = tid & 255;
    int tid8 = (bid - MAXT256 * 16) * 2 + tsel;
    int e = tid8 >> 10, rem = tid8 & 1023;
    const int R = 4096, C = 1024;
    int c0 = (rem & 15) * 64, r0 = (rem >> 4) * 64;
    const float* src = w2 + (size_t)e * R * C;
    unsigned short* dst = w2t + (size_t)e * R * C;
    float (*tile)[65] = (float(*)[65])(lds + tsel * 20480);
    int rr = tid2 >> 4, cc4 = (tid2 & 15) * 4;
#pragma unroll
    for (int i = 0; i < 4; ++i) {
      f32x4 v = *(const f32x4*)(src + (size_t)(r0 + rr + i * 16) * C + c0 + cc4);
#pragma unroll
      for (int j = 0; j < 4; ++j) tile[rr + i * 16][cc4 + j] = v[j];
    }
    __syncthreads();
    int cc = tid2 >> 3, rr8 = (tid2 & 7) * 8;
#pragma unroll
    for (int i = 0; i < 2; ++i) {
      int c = cc + i * 32;
      u16x8 u;
#pragma unroll
      for (int j = 0; j < 8; ++j) u[j] = f2bf(tile[rr8 + j][c]);
      *(u16x8*)(dst + (size_t)(c0 + c) * R + r0 + rr8) = u;
    }
    return;
  }

  // ------------------------- FFN1 GEMM (R9 body) -------------------------
  constexpr int KDIM = D_MODEL, NDIM = D_FF;
  constexpr int NT = KDIM / 64;
  constexpr int SK = KDIM * 2;
  const int NP = NDIM / 256;
  int ntiles = meta[25];
  int nwg = ntiles * NP;
  int orig = bid;
  if (orig >= nwg) return;
  int wid = xcd_swz(orig, nwg);
  int nb = wid % NP, t = wid / NP;           // t-outer, nb-inner (L2 A-share)

  int e = meta[32 + t];
  int lm = meta[112 + t];
  int off = meta[8 + e];
  int rowsValid = meta[9 + e] - off - lm * 256;
  int m0 = off + lm * 256;

  int lane = tid & 63, wv = tid >> 6;
  int waveM = wv >> 2, waveN = wv & 3;
  int lr = lane & 15, lg = lane >> 4;

  const char* aBase = (const char*)(A + (size_t)m0 * KDIM);
  const char* bBase = (const char*)(Bt + ((size_t)e * NDIM + nb * 256) * KDIM);

  const int o0 = tid * 16, o1 = o0 + 8192;
  const int lw0 = o0 >> 7, lw1 = o1 >> 7;
  const int co0 = (o0 & 127) ^ ((lw0 & 7) << 4);
  const int co1 = (o1 & 127) ^ ((lw1 & 7) << 4);
  const int mA0 = (lw0 >> 6) * 128 + (lw0 & 63), mA1 = (lw1 >> 6) * 128 + (lw1 & 63);
  const int nB0 = (lw0 >> 5) * 64 + (lw0 & 31), nB1 = (lw1 >> 5) * 64 + (lw1 & 31);

#define ST_A(D, R, KT) { \
    char* _d = lds + (D) * 65536 + (R) * 16384; \
    gload16(aBase + (size_t)(mA0 + (R) * 64) * SK + (KT) * 128 + co0, _d + o0); \
    gload16(aBase + (size_t)(mA1 + (R) * 64) * SK + (KT) * 128 + co1, _d + o1); }
#define ST_B(D, R, KT) { \
    char* _d = lds + (D) * 65536 + 32768 + (R) * 16384; \
    gload16(bBase + (size_t)(nB0 + (R) * 32) * SK + (KT) * 128 + co0, _d + o0); \
    gload16(bBase + (size_t)(nB1 + (R) * 32) * SK + (KT) * 128 + co1, _d + o1); }

  bf16x8 a[4][2], b0[2][2], b1[2][2];
#define LD_A(D, MH) { \
    const char* _b = lds + (D) * 65536 + (MH) * 16384; \
    _Pragma("unroll") for (int mfi = 0; mfi < 4; ++mfi) \
    _Pragma("unroll") for (int kq = 0; kq < 2; ++kq) { \
      int _o = (waveM * 64 + mfi * 16 + lr) * 128 + kq * 64 + lg * 16; \
      _o ^= ((_o >> 7) & 7) << 4; \
      a[mfi][kq] = *(const bf16x8*)(_b + _o); } }
#define LD_B(D, NH, BV) { \
    const char* _b = lds + (D) * 65536 + 32768 + (NH) * 16384; \
    _Pragma("unroll") for (int nfi = 0; nfi < 2; ++nfi) \
    _Pragma("unroll") for (int kq = 0; kq < 2; ++kq) { \
      int _o = (waveN * 32 + nfi * 16 + lr) * 128 + kq * 64 + lg * 16; \
      _o ^= ((_o >> 7) & 7) << 4; \
      BV[nfi][kq] = *(const bf16x8*)(_b + _o); } }

  f32x4 acc[8][4];
#pragma unroll
  for (int i = 0; i < 8; ++i)
#pragma unroll
    for (int j = 0; j < 4; ++j) acc[i][j] = (f32x4){0.f, 0.f, 0.f, 0.f};

#define MM(MH, NH, BV) { \
    __builtin_amdgcn_s_setprio(1); \
    _Pragma("unroll") for (int mfi = 0; mfi < 4; ++mfi) \
    _Pragma("unroll") for (int nfi = 0; nfi < 2; ++nfi) \
    _Pragma("unroll") for (int kq = 0; kq < 2; ++kq) \
      acc[(MH) * 4 + mfi][(NH) * 2 + nfi] = __builtin_amdgcn_mfma_f32_16x16x32_bf16( \
          a[mfi][kq], BV[nfi][kq], acc[(MH) * 4 + mfi][(NH) * 2 + nfi], 0, 0, 0); \
    __builtin_amdgcn_s_setprio(0); }

  {
    int k1 = NT > 1 ? 1 : 0;
    ST_A(0, 0, 0); ST_B(0, 1, 0); ST_A(0, 1, 0); ST_B(0, 0, 0);
    ST_A(1, 0, k1); ST_B(1, 1, k1); ST_A(1, 1, k1);
  }
  WAIT_VM(6); SBAR();

  for (int T = 0; T < NT; ++T) {
    int d = T & 1, dn = d ^ 1;
    int tp1 = T + 1 < NT ? T + 1 : T;
    int tp2 = T + 2 < NT ? T + 2 : T;
    LD_A(d, 0); LD_B(d, 0, b0);
    ST_B(dn, 0, tp1);
    SBAR();
    MM(0, 0, b0);
    SBAR();
    LD_B(d, 1, b1);
    ST_A(d, 0, tp2);
    SBAR();
    MM(0, 1, b1);
    SBAR();
    LD_A(d, 1);
    ST_B(d, 1, tp2);
    SBAR();
    MM(1, 1, b1);
    SBAR();
    ST_A(d, 1, tp2);
    SBAR();
    MM(1, 0, b0);
    WAIT_VM(6);
    SBAR();
  }
  asm volatile("s_waitcnt vmcnt(0)" ::: "memory");

  int cb = nb * 256 + waveN * 64;
#pragma unroll
  for (int mf = 0; mf < 8; ++mf) {
#pragma unroll
    for (int rg = 0; rg < 4; ++rg) {
      int rowt = waveM * 128 + mf * 16 + lg * 4 + rg;
      if (rowt >= rowsValid) continue;
      size_t ro = (size_t)(m0 + rowt) * NDIM;
#pragma unroll
      for (int nf = 0; nf < 4; ++nf) {
        int col = cb + nf * 16 + lr;
        float v = acc[mf][nf][rg] + bias[e * NDIM + col];
        H[ro + col] = f2bf(fmaxf(v, 0.f));
      }
    }
  }
#undef ST_A
#undef ST_B
#undef LD_A
#undef LD_B
#undef MM
}

// ---------------- FFN2: 256x256 grouped GEMM (R9 body) ----------------------
template<int KDIM, int NDIM>
__global__ __launch_bounds__(512, 1) void gemm8_ffn2(
    const unsigned short* __restrict__ A, const unsigned short* __restrict__ Bt,
    const float* __restrict__ bias, const int* __restrict__ meta,
    const int* __restrict__ perm, float* __restrict__ Out) {
  constexpr int NT = KDIM / 64;
  constexpr int SK = KDIM * 2;
  const int NP = NDIM / 256;
  int ntiles = meta[25];
  int nwg = ntiles * NP;
  int orig = blockIdx.x;
  if (orig >= nwg) return;
  int wid = xcd_swz(orig, nwg);
  int nb = wid % NP, t = wid / NP;           // t-outer, nb-inner (L2 A-share)

  int e = meta[32 + t];
  int lm = meta[112 + t];
  int off = meta[8 + e];
  int rowsValid = meta[9 + e] - off - lm * 256;
  int m0 = off + lm * 256;

  __shared__ char lds[131072];

  int tid = threadIdx.x;
  int lane = tid & 63, wv = tid >> 6;
  int waveM = wv >> 2, waveN = wv & 3;
  int lr = lane & 15, lg = lane >> 4;

  const char* aBase = (const char*)(A + (size_t)m0 * KDIM);
  const char* bBase = (const char*)(Bt + ((size_t)e * NDIM + nb * 256) * KDIM);

  const int o0 = tid * 16, o1 = o0 + 8192;
  const int lw0 = o0 >> 7, lw1 = o1 >> 7;
  const int co0 = (o0 & 127) ^ ((lw0 & 7) << 4);
  const int co1 = (o1 & 127) ^ ((lw1 & 7) << 4);
  const int mA0 = (lw0 >> 6) * 128 + (lw0 & 63), mA1 = (lw1 >> 6) * 128 + (lw1 & 63);
  const int nB0 = (lw0 >> 5) * 64 + (lw0 & 31), nB1 = (lw1 >> 5) * 64 + (lw1 & 31);

#define ST_A(D, R, KT) { \
    char* _d = lds + (D) * 65536 + (R) * 16384; \
    gload16(aBase + (size_t)(mA0 + (R) * 64) * SK + (KT) * 128 + co0, _d + o0); \
    gload16(aBase + (size_t)(mA1 + (R) * 64) * SK + (KT) * 128 + co1, _d + o1); }
#define ST_B(D, R, KT) { \
    char* _d = lds + (D) * 65536 + 32768 + (R) * 16384; \
    gload16(bBase + (size_t)(nB0 + (R) * 32) * SK + (KT) * 128 + co0, _d + o0); \
    gload16(bBase + (size_t)(nB1 + (R) * 32) * SK + (KT) * 128 + co1, _d + o1); }

  bf16x8 a[4][2], b0[2][2], b1[2][2];
#define LD_A(D, MH) { \
    const char* _b = lds + (D) * 65536 + (MH) * 16384; \
    _Pragma("unroll") for (int mfi = 0; mfi < 4; ++mfi) \
    _Pragma("unroll") for (int kq = 0; kq < 2; ++kq) { \
      int _o = (waveM * 64 + mfi * 16 + lr) * 128 + kq * 64 + lg * 16; \
      _o ^= ((_o >> 7) & 7) << 4; \
      a[mfi][kq] = *(const bf16x8*)(_b + _o); } }
#define LD_B(D, NH, BV) { \
    const char* _b = lds + (D) * 65536 + 32768 + (NH) * 16384; \
    _Pragma("unroll") for (int nfi = 0; nfi < 2; ++nfi) \
    _Pragma("unroll") for (int kq = 0; kq < 2; ++kq) { \
      int _o = (waveN * 32 + nfi * 16 + lr) * 128 + kq * 64 + lg * 16; \
      _o ^= ((_o >> 7) & 7) << 4; \
      BV[nfi][kq] = *(const bf16x8*)(_b + _o); } }

  f32x4 acc[8][4];
#pragma unroll
  for (int i = 0; i < 8; ++i)
#pragma unroll
    for (int j = 0; j < 4; ++j) acc[i][j] = (f32x4){0.f, 0.f, 0.f, 0.f};

#define MM(MH, NH, BV) { \
    __builtin_amdgcn_s_setprio(1); \
    _Pragma("unroll") for (int mfi = 0; mfi < 4; ++mfi) \
    _Pragma("unroll") for (int nfi = 0; nfi < 2; ++nfi) \
    _Pragma("unroll") for (int kq = 0; kq < 2; ++kq) \
      acc[(MH) * 4 + mfi][(NH) * 2 + nfi] = __builtin_amdgcn_mfma_f32_16x16x32_bf16( \
          a[mfi][kq], BV[nfi][kq], acc[(MH) * 4 + mfi][(NH) * 2 + nfi], 0, 0, 0); \
    __builtin_amdgcn_s_setprio(0); }

  {
    int k1 = NT > 1 ? 1 : 0;
    ST_A(0, 0, 0); ST_B(0, 1, 0); ST_A(0, 1, 0); ST_B(0, 0, 0);
    ST_A(1, 0, k1); ST_B(1, 1, k1); ST_A(1, 1, k1);
  }
  WAIT_VM(6); SBAR();

  for (int T = 0; T < NT; ++T) {
    int d = T & 1, dn = d ^ 1;
    int tp1 = T + 1 < NT ? T + 1 : T;
    int tp2 = T + 2 < NT ? T + 2 : T;
    LD_A(d, 0); LD_B(d, 0, b0);
    ST_B(dn, 0, tp1);
    SBAR();
    MM(0, 0, b0);
    SBAR();
    LD_B(d, 1, b1);
    ST_A(d, 0, tp2);
    SBAR();
    MM(0, 1, b1);
    SBAR();
    LD_A(d, 1);
    ST_B(d, 1, tp2);
    SBAR();
    MM(1, 1, b1);
    SBAR();
    ST_A(d, 1, tp2);
    SBAR();
    MM(1, 0, b0);
    WAIT_VM(6);
    SBAR();
  }
  asm volatile("s_waitcnt vmcnt(0)" ::: "memory");

  int cb = nb * 256 + waveN * 64;
#pragma unroll
  for (int mf = 0; mf < 8; ++mf) {
#pragma unroll
    for (int rg = 0; rg < 4; ++rg) {
      int rowt = waveM * 128 + mf * 16 + lg * 4 + rg;
      if (rowt >= rowsValid) continue;
      int tok = perm[m0 + rowt];
      size_t ro = (size_t)tok * NDIM;
#pragma unroll
      for (int nf = 0; nf < 4; ++nf) {
        int col = cb + nf * 16 + lr;
        Out[ro + col] = acc[mf][nf][rg] + bias[e * NDIM + col];
      }
    }
  }
#undef ST_A
#undef ST_B
#undef LD_A
#undef LD_B
#undef MM
}

extern "C" void kernel_launch(void* const* d_in, const int* in_sizes, int n_in,
                              void* d_out, int out_size, void* d_ws, size_t ws_size,
                              hipStream_t stream) {
  const float* x  = (const float*)d_in[0];
  const float* gw = (const float*)d_in[1];
  const float* gb = (const float*)d_in[2];
  const float* eb = (const float*)d_in[3];
  const float* w1 = (const float*)d_in[4];
  const float* b1 = (const float*)d_in[5];
  const float* w2 = (const float*)d_in[6];
  const float* b2 = (const float*)d_in[7];
  float* out = (float*)d_out;

  char* ws = (char*)d_ws;
  int* meta = (int*)(ws + OFF_META);
  int* topi = (int*)(ws + OFF_TOPI);
  int* perm = (int*)(ws + OFF_PERM);
  int* pos  = (int*)(ws + OFF_POS);
  unsigned short* xg  = (unsigned short*)(ws + OFF_XG);
  unsigned short* h   = (unsigned short*)(ws + OFF_H);
  unsigned short* w1t = (unsigned short*)(ws + OFF_W1T);
  unsigned short* w2t = (unsigned short*)(ws + OFF_W2T);

  hipLaunchKernelGGL(het_gate_w1t, dim3(2048 + 8192), dim3(256), 0, stream,
                     x, gw, gb, eb, topi, w1, w1t);
  hipLaunchKernelGGL(rank_kernel, dim3(1), dim3(1024), 0, stream, topi, meta, pos, perm);
  hipLaunchKernelGGL(scatter_kernel, dim3(NTOK), dim3(256), 0, stream, x, pos, xg);
  hipLaunchKernelGGL(ffn1_het, dim3(MAXT256 * 16 + 4096), dim3(512), 0, stream,
                     xg, w1t, b1, meta, h, w2, w2t);
  hipLaunchKernelGGL((gemm8_ffn2<D_FF, D_MODEL>), dim3(MAXT256 * (D_MODEL / 256)), dim3(512), 0, stream,
                     h, w2t, b2, meta, perm, out);
}